// Round 3
// baseline (3054.863 us; speedup 1.0000x reference)
//
#include <hip/hip_runtime.h>
#include <stdint.h>
#include <stddef.h>

#define N_NODES 100000
#define N_EDGES 1600000
#define IN_CH 128
#define HID_CH 128
#define OUT_CH 40

// ---------------- threefry2x32 (JAX PRNG, key = (0,42)) ----------------
__device__ __forceinline__ uint32_t rotl32(uint32_t x, int r) {
    return (x << r) | (x >> (32 - r));
}

__device__ __forceinline__ void threefry2x32_k42(uint32_t x0, uint32_t x1,
                                                 uint32_t& o0, uint32_t& o1) {
    const uint32_t ks0 = 0u, ks1 = 42u;
    const uint32_t ks2 = 0u ^ 42u ^ 0x1BD11BDAu;
    x0 += ks0; x1 += ks1;
    x0 += x1; x1 = rotl32(x1, 13); x1 ^= x0;
    x0 += x1; x1 = rotl32(x1, 15); x1 ^= x0;
    x0 += x1; x1 = rotl32(x1, 26); x1 ^= x0;
    x0 += x1; x1 = rotl32(x1,  6); x1 ^= x0;
    x0 += ks1; x1 += ks2 + 1u;
    x0 += x1; x1 = rotl32(x1, 17); x1 ^= x0;
    x0 += x1; x1 = rotl32(x1, 29); x1 ^= x0;
    x0 += x1; x1 = rotl32(x1, 16); x1 ^= x0;
    x0 += x1; x1 = rotl32(x1, 24); x1 ^= x0;
    x0 += ks2; x1 += ks0 + 2u;
    x0 += x1; x1 = rotl32(x1, 13); x1 ^= x0;
    x0 += x1; x1 = rotl32(x1, 15); x1 ^= x0;
    x0 += x1; x1 = rotl32(x1, 26); x1 ^= x0;
    x0 += x1; x1 = rotl32(x1,  6); x1 ^= x0;
    x0 += ks0; x1 += ks1 + 3u;
    x0 += x1; x1 = rotl32(x1, 17); x1 ^= x0;
    x0 += x1; x1 = rotl32(x1, 29); x1 ^= x0;
    x0 += x1; x1 = rotl32(x1, 16); x1 ^= x0;
    x0 += x1; x1 = rotl32(x1, 24); x1 ^= x0;
    x0 += ks1; x1 += ks2 + 4u;
    x0 += x1; x1 = rotl32(x1, 13); x1 ^= x0;
    x0 += x1; x1 = rotl32(x1, 15); x1 ^= x0;
    x0 += x1; x1 = rotl32(x1, 26); x1 ^= x0;
    x0 += x1; x1 = rotl32(x1,  6); x1 ^= x0;
    x0 += ks2; x1 += ks0 + 5u;
    o0 = x0; o1 = x1;
}

// Partitionable threefry (JAX default since 0.4.30), 32-bit draw:
// block = threefry2x32(key, (hi32(i), lo32(i))); bits[i] = block.x ^ block.y
// (XOR-fold of the two output words).  keep iff MSB(bits)==0 (uniform<0.5).
__device__ __forceinline__ float dropout_apply(float v, uint32_t idx) {
    uint32_t o0, o1;
    threefry2x32_k42(0u, idx, o0, o1);
    uint32_t bits = o0 ^ o1;
    return (bits & 0x80000000u) ? 0.0f : v * 2.0f;
}

// ---------------- edge dtype detection ----------------
// If edges are raw int64 (values < 2^31), every odd 32-bit word is 0.
// If int32, odd words are random node ids (~half nonzero).  Scan stays
// within the first 12.8 MB, valid under both layouts.
// flag != 0  =>  int32 layout.
__global__ void detect_int64(const int* __restrict__ ei32, int* __restrict__ flag) {
    int i = blockIdx.x * blockDim.x + threadIdx.x;
    int stride = gridDim.x * blockDim.x;
    int local = 0;
    for (int k = i; k < N_EDGES; k += stride) local |= ei32[2 * k + 1];
    if (local) atomicOr(flag, 1);
}

__device__ __forceinline__ void load_edge(const void* ei, bool is32, int e,
                                          int& s, int& d) {
    if (is32) {
        const int* p = (const int*)ei;
        s = p[e]; d = p[N_EDGES + e];
    } else {
        const long long* p = (const long long*)ei;
        s = (int)p[e]; d = (int)p[N_EDGES + e];
    }
}

// ---------------- utility kernels ----------------
__global__ void zero_f32(float* __restrict__ p, long n) {
    long i = (long)blockIdx.x * blockDim.x + threadIdx.x;
    long stride = (long)gridDim.x * blockDim.x;
    for (; i < n; i += stride) p[i] = 0.0f;
}

__global__ void deg_count(const void* __restrict__ ei, const int* __restrict__ flag,
                          float* __restrict__ deg) {
    bool is32 = (*flag != 0);
    int i = blockIdx.x * blockDim.x + threadIdx.x;
    int stride = gridDim.x * blockDim.x;
    for (; i < N_EDGES; i += stride) {
        int s, d;
        load_edge(ei, is32, i, s, d);
        atomicAdd(&deg[d], 1.0f);
    }
}

__global__ void inv_transform(float* __restrict__ deg, int n) {
    int i = blockIdx.x * blockDim.x + threadIdx.x;
    if (i < n) {
        float d = deg[i];
        deg[i] = (d > 0.0f) ? (1.0f / d) : 0.0f;
    }
}

// one wave per edge: gather 128-ch feature row, atomic-add into agg[dst]
__global__ __launch_bounds__(256) void scatter_add(
    const float* __restrict__ feat, const void* __restrict__ ei,
    const int* __restrict__ flag, float* __restrict__ agg, int n_edges) {
    bool is32 = (*flag != 0);
    int gid = blockIdx.x * blockDim.x + threadIdx.x;
    int wave = gid >> 6;
    int lane = threadIdx.x & 63;
    int n_waves = (gridDim.x * blockDim.x) >> 6;
    for (int e = wave; e < n_edges; e += n_waves) {
        int s, d;
        load_edge(ei, is32, e, s, d);
        const float2 v = *reinterpret_cast<const float2*>(feat + (size_t)s * 128 + lane * 2);
        float* o = agg + (size_t)d * 128 + lane * 2;
        atomicAdd(o, v.x);
        atomicAdd(o + 1, v.y);
    }
}

// ---------------- layer 1: h = dropout(relu([agg*inv | x] @ [W1l;W1r] + b1)) ----------------
__global__ __launch_bounds__(256) void layer1_kernel(
    const float* __restrict__ agg, const float* __restrict__ x,
    const float* __restrict__ inv_deg, const float* __restrict__ W1l,
    const float* __restrict__ W1r, const float* __restrict__ b1,
    float* __restrict__ h) {
    __shared__ float a_tile[64][65];
    __shared__ float w_tile[64][128];
    const int t = threadIdx.x;
    const int node0 = blockIdx.x * 64;
    const int tr = t >> 4;
    const int tc = t & 15;

    float acc[4][8];
    #pragma unroll
    for (int m = 0; m < 4; ++m)
        #pragma unroll
        for (int r = 0; r < 8; ++r) acc[m][r] = 0.0f;

    for (int kc = 0; kc < 256; kc += 64) {
        #pragma unroll
        for (int i = 0; i < 4; ++i) {
            int idx = t + i * 256;
            int row = idx >> 4;
            int c4  = idx & 15;
            int n = node0 + row;
            int nc = (n < N_NODES) ? n : (N_NODES - 1);
            float4 v;
            if (kc < 128) {
                v = *reinterpret_cast<const float4*>(agg + (size_t)nc * 128 + kc + c4 * 4);
                float s = inv_deg[nc];
                v.x *= s; v.y *= s; v.z *= s; v.w *= s;
            } else {
                v = *reinterpret_cast<const float4*>(x + (size_t)nc * 128 + (kc - 128) + c4 * 4);
            }
            a_tile[row][c4 * 4 + 0] = v.x;
            a_tile[row][c4 * 4 + 1] = v.y;
            a_tile[row][c4 * 4 + 2] = v.z;
            a_tile[row][c4 * 4 + 3] = v.w;
        }
        #pragma unroll
        for (int i = 0; i < 8; ++i) {
            int idx = t + i * 256;
            int row = idx >> 5;
            int c4  = idx & 31;
            int k = kc + row;
            const float* Wsrc = (k < 128) ? (W1l + (size_t)k * 128)
                                          : (W1r + (size_t)(k - 128) * 128);
            float4 v = *reinterpret_cast<const float4*>(Wsrc + c4 * 4);
            *reinterpret_cast<float4*>(&w_tile[row][c4 * 4]) = v;
        }
        __syncthreads();
        #pragma unroll
        for (int kk = 0; kk < 64; ++kk) {
            float a0 = a_tile[tr * 4 + 0][kk];
            float a1 = a_tile[tr * 4 + 1][kk];
            float a2 = a_tile[tr * 4 + 2][kk];
            float a3 = a_tile[tr * 4 + 3][kk];
            float4 w0 = *reinterpret_cast<const float4*>(&w_tile[kk][tc * 8]);
            float4 w1 = *reinterpret_cast<const float4*>(&w_tile[kk][tc * 8 + 4]);
            float wv[8] = {w0.x, w0.y, w0.z, w0.w, w1.x, w1.y, w1.z, w1.w};
            #pragma unroll
            for (int r = 0; r < 8; ++r) {
                acc[0][r] += a0 * wv[r];
                acc[1][r] += a1 * wv[r];
                acc[2][r] += a2 * wv[r];
                acc[3][r] += a3 * wv[r];
            }
        }
        __syncthreads();
    }
    #pragma unroll
    for (int m = 0; m < 4; ++m) {
        int n = node0 + tr * 4 + m;
        if (n < N_NODES) {
            #pragma unroll
            for (int r = 0; r < 8; ++r) {
                int j = tc * 8 + r;
                float v = acc[m][r] + b1[j];
                v = (v > 0.0f) ? v : 0.0f;
                v = dropout_apply(v, (uint32_t)(n * 128 + j));
                h[(size_t)n * 128 + j] = v;
            }
        }
    }
}

// ---------------- layer 2: out = log_softmax([agg*inv | h] @ [W2l;W2r] + b2) ----------------
__global__ __launch_bounds__(256) void layer2_kernel(
    const float* __restrict__ agg, const float* __restrict__ h,
    const float* __restrict__ inv_deg, const float* __restrict__ W2l,
    const float* __restrict__ W2r, const float* __restrict__ b2,
    float* __restrict__ out) {
    __shared__ float a_tile[128][65];
    __shared__ float w_tile[64][40];
    const int t = threadIdx.x;
    const int node0 = blockIdx.x * 128;
    const int tr = t >> 3;
    const int tc = t & 7;

    float acc[4][5];
    #pragma unroll
    for (int m = 0; m < 4; ++m)
        #pragma unroll
        for (int r = 0; r < 5; ++r) acc[m][r] = 0.0f;

    for (int kc = 0; kc < 256; kc += 64) {
        #pragma unroll
        for (int i = 0; i < 8; ++i) {
            int idx = t + i * 256;
            int row = idx >> 4;
            int c4  = idx & 15;
            int n = node0 + row;
            int nc = (n < N_NODES) ? n : (N_NODES - 1);
            float4 v;
            if (kc < 128) {
                v = *reinterpret_cast<const float4*>(agg + (size_t)nc * 128 + kc + c4 * 4);
                float s = inv_deg[nc];
                v.x *= s; v.y *= s; v.z *= s; v.w *= s;
            } else {
                v = *reinterpret_cast<const float4*>(h + (size_t)nc * 128 + (kc - 128) + c4 * 4);
            }
            a_tile[row][c4 * 4 + 0] = v.x;
            a_tile[row][c4 * 4 + 1] = v.y;
            a_tile[row][c4 * 4 + 2] = v.z;
            a_tile[row][c4 * 4 + 3] = v.w;
        }
        #pragma unroll
        for (int i = 0; i < 10; ++i) {
            int idx = t + i * 256;
            int row = idx / 40;
            int col = idx % 40;
            int k = kc + row;
            float v = (k < 128) ? W2l[(size_t)k * 40 + col]
                                : W2r[(size_t)(k - 128) * 40 + col];
            w_tile[row][col] = v;
        }
        __syncthreads();
        #pragma unroll
        for (int kk = 0; kk < 64; ++kk) {
            float a0 = a_tile[tr * 4 + 0][kk];
            float a1 = a_tile[tr * 4 + 1][kk];
            float a2 = a_tile[tr * 4 + 2][kk];
            float a3 = a_tile[tr * 4 + 3][kk];
            float w[5];
            #pragma unroll
            for (int r = 0; r < 5; ++r) w[r] = w_tile[kk][tc * 5 + r];
            #pragma unroll
            for (int r = 0; r < 5; ++r) {
                acc[0][r] += a0 * w[r];
                acc[1][r] += a1 * w[r];
                acc[2][r] += a2 * w[r];
                acc[3][r] += a3 * w[r];
            }
        }
        __syncthreads();
    }
    #pragma unroll
    for (int m = 0; m < 4; ++m) {
        int n = node0 + tr * 4 + m;
        float v[5];
        float mx = -1e30f;
        #pragma unroll
        for (int r = 0; r < 5; ++r) {
            v[r] = acc[m][r] + b2[tc * 5 + r];
            mx = fmaxf(mx, v[r]);
        }
        #pragma unroll
        for (int s = 1; s < 8; s <<= 1) mx = fmaxf(mx, __shfl_xor(mx, s, 64));
        float se = 0.0f;
        #pragma unroll
        for (int r = 0; r < 5; ++r) se += expf(v[r] - mx);
        #pragma unroll
        for (int s = 1; s < 8; s <<= 1) se += __shfl_xor(se, s, 64);
        float lz = mx + logf(se);
        if (n < N_NODES) {
            #pragma unroll
            for (int r = 0; r < 5; ++r)
                out[(size_t)n * 40 + tc * 5 + r] = v[r] - lz;
        }
    }
}

// ---------------- launch ----------------
extern "C" void kernel_launch(void* const* d_in, const int* in_sizes, int n_in,
                              void* d_out, int out_size, void* d_ws, size_t ws_size,
                              hipStream_t stream) {
    const float* x   = (const float*)d_in[0];
    const void*  ei  = d_in[1];
    const float* W1l = (const float*)d_in[2];
    const float* b1  = (const float*)d_in[3];
    const float* W1r = (const float*)d_in[4];
    const float* W2l = (const float*)d_in[5];
    const float* b2  = (const float*)d_in[6];
    const float* W2r = (const float*)d_in[7];
    float* out = (float*)d_out;

    char* ws = (char*)d_ws;
    float* inv_deg = (float*)ws;                      // 100000 f32
    int*   flag    = (int*)(ws + 400000);             // inside zeroed prefix pad
    float* agg     = (float*)(ws + 524288);           // 12.8M f32
    float* h       = (float*)(ws + 51724288);         // 12.8M f32

    // zero inv_deg + flag + agg (contiguous prefix of ws)
    zero_f32<<<2048, 256, 0, stream>>>((float*)ws, (524288 + 51200000) / 4);
    detect_int64<<<1024, 256, 0, stream>>>((const int*)ei, flag);
    deg_count<<<1024, 256, 0, stream>>>(ei, flag, inv_deg);
    inv_transform<<<(N_NODES + 255) / 256, 256, 0, stream>>>(inv_deg, N_NODES);
    scatter_add<<<2048, 256, 0, stream>>>(x, ei, flag, agg, N_EDGES);
    layer1_kernel<<<(N_NODES + 63) / 64, 256, 0, stream>>>(agg, x, inv_deg, W1l, W1r, b1, h);
    zero_f32<<<2048, 256, 0, stream>>>(agg, 12800000L);
    scatter_add<<<2048, 256, 0, stream>>>(h, ei, flag, agg, N_EDGES);
    layer2_kernel<<<(N_NODES + 127) / 128, 256, 0, stream>>>(agg, h, inv_deg, W2l, W2r, b2, out);
}

// Round 4
// 745.838 us; speedup vs baseline: 4.0959x; 4.0959x over previous
//
#include <hip/hip_runtime.h>
#include <stdint.h>
#include <stddef.h>

#define N_NODES 100000
#define N_EDGES 1600000
#define IN_CH 128
#define HID_CH 128
#define OUT_CH 40
#define NB_SCAN 391   // ceil(N_NODES/256)

// ---------------- threefry2x32 (JAX PRNG, key = (0,42)) ----------------
__device__ __forceinline__ uint32_t rotl32(uint32_t x, int r) {
    return (x << r) | (x >> (32 - r));
}

__device__ __forceinline__ void threefry2x32_k42(uint32_t x0, uint32_t x1,
                                                 uint32_t& o0, uint32_t& o1) {
    const uint32_t ks0 = 0u, ks1 = 42u;
    const uint32_t ks2 = 0u ^ 42u ^ 0x1BD11BDAu;
    x0 += ks0; x1 += ks1;
    x0 += x1; x1 = rotl32(x1, 13); x1 ^= x0;
    x0 += x1; x1 = rotl32(x1, 15); x1 ^= x0;
    x0 += x1; x1 = rotl32(x1, 26); x1 ^= x0;
    x0 += x1; x1 = rotl32(x1,  6); x1 ^= x0;
    x0 += ks1; x1 += ks2 + 1u;
    x0 += x1; x1 = rotl32(x1, 17); x1 ^= x0;
    x0 += x1; x1 = rotl32(x1, 29); x1 ^= x0;
    x0 += x1; x1 = rotl32(x1, 16); x1 ^= x0;
    x0 += x1; x1 = rotl32(x1, 24); x1 ^= x0;
    x0 += ks2; x1 += ks0 + 2u;
    x0 += x1; x1 = rotl32(x1, 13); x1 ^= x0;
    x0 += x1; x1 = rotl32(x1, 15); x1 ^= x0;
    x0 += x1; x1 = rotl32(x1, 26); x1 ^= x0;
    x0 += x1; x1 = rotl32(x1,  6); x1 ^= x0;
    x0 += ks0; x1 += ks1 + 3u;
    x0 += x1; x1 = rotl32(x1, 17); x1 ^= x0;
    x0 += x1; x1 = rotl32(x1, 29); x1 ^= x0;
    x0 += x1; x1 = rotl32(x1, 16); x1 ^= x0;
    x0 += x1; x1 = rotl32(x1, 24); x1 ^= x0;
    x0 += ks1; x1 += ks2 + 4u;
    x0 += x1; x1 = rotl32(x1, 13); x1 ^= x0;
    x0 += x1; x1 = rotl32(x1, 15); x1 ^= x0;
    x0 += x1; x1 = rotl32(x1, 26); x1 ^= x0;
    x0 += x1; x1 = rotl32(x1,  6); x1 ^= x0;
    x0 += ks2; x1 += ks0 + 5u;
    o0 = x0; o1 = x1;
}

// Partitionable threefry bits[i] = o0 ^ o1 of block(counts=(0,i)).
// keep iff MSB==0.  (Validated in round 3: absmax 0.031.)
__device__ __forceinline__ float dropout_apply(float v, uint32_t idx) {
    uint32_t o0, o1;
    threefry2x32_k42(0u, idx, o0, o1);
    uint32_t bits = o0 ^ o1;
    return (bits & 0x80000000u) ? 0.0f : v * 2.0f;
}

// ---------------- edge dtype detection ----------------
__global__ void detect_int64(const int* __restrict__ ei32, int* __restrict__ flag) {
    int i = blockIdx.x * blockDim.x + threadIdx.x;
    int stride = gridDim.x * blockDim.x;
    int local = 0;
    for (int k = i; k < N_EDGES; k += stride) local |= ei32[2 * k + 1];
    if (local) atomicOr(flag, 1);
}

__device__ __forceinline__ void load_edge(const void* ei, bool is32, int e,
                                          int& s, int& d) {
    if (is32) {
        const int* p = (const int*)ei;
        s = p[e]; d = p[N_EDGES + e];
    } else {
        const long long* p = (const long long*)ei;
        s = (int)p[e]; d = (int)p[N_EDGES + e];
    }
}

// ---------------- CSR build ----------------
__global__ void zero_i32(int* __restrict__ p, int n) {
    int i = blockIdx.x * blockDim.x + threadIdx.x;
    int stride = gridDim.x * blockDim.x;
    for (; i < n; i += stride) p[i] = 0;
}

__global__ void deg_count(const void* __restrict__ ei, const int* __restrict__ flag,
                          int* __restrict__ deg) {
    bool is32 = (*flag != 0);
    int i = blockIdx.x * blockDim.x + threadIdx.x;
    int stride = gridDim.x * blockDim.x;
    for (; i < N_EDGES; i += stride) {
        int s, d;
        load_edge(ei, is32, i, s, d);
        atomicAdd(&deg[d], 1);
    }
}

// per-block sum of 256 degrees
__global__ void scan1(const int* __restrict__ deg, int* __restrict__ bsum) {
    __shared__ int s[256];
    int t = threadIdx.x;
    int i = blockIdx.x * 256 + t;
    s[t] = (i < N_NODES) ? deg[i] : 0;
    __syncthreads();
    for (int off = 128; off; off >>= 1) {
        if (t < off) s[t] += s[t + off];
        __syncthreads();
    }
    if (t == 0) bsum[blockIdx.x] = s[0];
}

// single-block exclusive scan of block sums (NB_SCAN <= 512)
__global__ void scan2(int* __restrict__ bsum) {
    __shared__ int s[512];
    int t = threadIdx.x;
    int v = (t < NB_SCAN) ? bsum[t] : 0;
    s[t] = v;
    __syncthreads();
    for (int off = 1; off < 512; off <<= 1) {
        int a = (t >= off) ? s[t - off] : 0;
        __syncthreads();
        s[t] += a;
        __syncthreads();
    }
    if (t < NB_SCAN) bsum[t] = s[t] - v;   // exclusive
}

// per-element: cursor[i] = exclusive prefix (start of node i's bucket)
__global__ void scan3(const int* __restrict__ deg, const int* __restrict__ bsum,
                      int* __restrict__ cursor) {
    __shared__ int s[256];
    int t = threadIdx.x;
    int i = blockIdx.x * 256 + t;
    int v = (i < N_NODES) ? deg[i] : 0;
    s[t] = v;
    __syncthreads();
    for (int off = 1; off < 256; off <<= 1) {
        int a = (t >= off) ? s[t - off] : 0;
        __syncthreads();
        s[t] += a;
        __syncthreads();
    }
    if (i < N_NODES) cursor[i] = bsum[blockIdx.x] + s[t] - v;
}

// after fill completes, cursor[n] == end of node n's bucket
__global__ void csr_fill(const void* __restrict__ ei, const int* __restrict__ flag,
                         int* __restrict__ cursor, int* __restrict__ csr) {
    bool is32 = (*flag != 0);
    int i = blockIdx.x * blockDim.x + threadIdx.x;
    int stride = gridDim.x * blockDim.x;
    for (; i < N_EDGES; i += stride) {
        int s, d;
        load_edge(ei, is32, i, s, d);
        int p = atomicAdd(&cursor[d], 1);
        csr[p] = s;
    }
}

// ---------------- gather-based mean aggregation (no atomics) ----------------
__device__ __forceinline__ float2 ldf2(const float* p) {
    return *reinterpret_cast<const float2*>(p);
}

__global__ __launch_bounds__(256) void aggregate_mean(
    const float* __restrict__ feat, const int* __restrict__ csr,
    const int* __restrict__ cursor, float* __restrict__ out) {
    int node = blockIdx.x * 4 + (threadIdx.x >> 6);
    if (node >= N_NODES) return;
    int lane = threadIdx.x & 63;
    int beg = (node > 0) ? cursor[node - 1] : 0;
    int end = cursor[node];
    float ax0 = 0, ay0 = 0, ax1 = 0, ay1 = 0;
    float ax2 = 0, ay2 = 0, ax3 = 0, ay3 = 0;
    int e = beg;
    for (; e + 4 <= end; e += 4) {
        int s0 = csr[e], s1 = csr[e + 1], s2 = csr[e + 2], s3 = csr[e + 3];
        float2 v0 = ldf2(feat + (size_t)s0 * 128 + lane * 2);
        float2 v1 = ldf2(feat + (size_t)s1 * 128 + lane * 2);
        float2 v2 = ldf2(feat + (size_t)s2 * 128 + lane * 2);
        float2 v3 = ldf2(feat + (size_t)s3 * 128 + lane * 2);
        ax0 += v0.x; ay0 += v0.y;
        ax1 += v1.x; ay1 += v1.y;
        ax2 += v2.x; ay2 += v2.y;
        ax3 += v3.x; ay3 += v3.y;
    }
    for (; e < end; ++e) {
        float2 v = ldf2(feat + (size_t)csr[e] * 128 + lane * 2);
        ax0 += v.x; ay0 += v.y;
    }
    int deg = end - beg;
    float inv = (deg > 0) ? (1.0f / (float)deg) : 0.0f;
    float2 r;
    r.x = (ax0 + ax1 + ax2 + ax3) * inv;
    r.y = (ay0 + ay1 + ay2 + ay3) * inv;
    *reinterpret_cast<float2*>(out + (size_t)node * 128 + lane * 2) = r;
}

// ---------------- layer 1: h = dropout(relu([agg | x] @ [W1l;W1r] + b1)) ----------------
__global__ __launch_bounds__(256) void layer1_kernel(
    const float* __restrict__ agg, const float* __restrict__ x,
    const float* __restrict__ W1l, const float* __restrict__ W1r,
    const float* __restrict__ b1, float* __restrict__ h) {
    __shared__ float a_tile[64][65];
    __shared__ float w_tile[64][128];
    const int t = threadIdx.x;
    const int node0 = blockIdx.x * 64;
    const int tr = t >> 4;
    const int tc = t & 15;

    float acc[4][8];
    #pragma unroll
    for (int m = 0; m < 4; ++m)
        #pragma unroll
        for (int r = 0; r < 8; ++r) acc[m][r] = 0.0f;

    for (int kc = 0; kc < 256; kc += 64) {
        #pragma unroll
        for (int i = 0; i < 4; ++i) {
            int idx = t + i * 256;
            int row = idx >> 4;
            int c4  = idx & 15;
            int n = node0 + row;
            int nc = (n < N_NODES) ? n : (N_NODES - 1);
            float4 v;
            if (kc < 128) {
                v = *reinterpret_cast<const float4*>(agg + (size_t)nc * 128 + kc + c4 * 4);
            } else {
                v = *reinterpret_cast<const float4*>(x + (size_t)nc * 128 + (kc - 128) + c4 * 4);
            }
            a_tile[row][c4 * 4 + 0] = v.x;
            a_tile[row][c4 * 4 + 1] = v.y;
            a_tile[row][c4 * 4 + 2] = v.z;
            a_tile[row][c4 * 4 + 3] = v.w;
        }
        #pragma unroll
        for (int i = 0; i < 8; ++i) {
            int idx = t + i * 256;
            int row = idx >> 5;
            int c4  = idx & 31;
            int k = kc + row;
            const float* Wsrc = (k < 128) ? (W1l + (size_t)k * 128)
                                          : (W1r + (size_t)(k - 128) * 128);
            float4 v = *reinterpret_cast<const float4*>(Wsrc + c4 * 4);
            *reinterpret_cast<float4*>(&w_tile[row][c4 * 4]) = v;
        }
        __syncthreads();
        #pragma unroll
        for (int kk = 0; kk < 64; ++kk) {
            float a0 = a_tile[tr * 4 + 0][kk];
            float a1 = a_tile[tr * 4 + 1][kk];
            float a2 = a_tile[tr * 4 + 2][kk];
            float a3 = a_tile[tr * 4 + 3][kk];
            float4 w0 = *reinterpret_cast<const float4*>(&w_tile[kk][tc * 8]);
            float4 w1 = *reinterpret_cast<const float4*>(&w_tile[kk][tc * 8 + 4]);
            float wv[8] = {w0.x, w0.y, w0.z, w0.w, w1.x, w1.y, w1.z, w1.w};
            #pragma unroll
            for (int r = 0; r < 8; ++r) {
                acc[0][r] += a0 * wv[r];
                acc[1][r] += a1 * wv[r];
                acc[2][r] += a2 * wv[r];
                acc[3][r] += a3 * wv[r];
            }
        }
        __syncthreads();
    }
    #pragma unroll
    for (int m = 0; m < 4; ++m) {
        int n = node0 + tr * 4 + m;
        if (n < N_NODES) {
            #pragma unroll
            for (int r = 0; r < 8; ++r) {
                int j = tc * 8 + r;
                float v = acc[m][r] + b1[j];
                v = (v > 0.0f) ? v : 0.0f;
                v = dropout_apply(v, (uint32_t)(n * 128 + j));
                h[(size_t)n * 128 + j] = v;
            }
        }
    }
}

// ---------------- layer 2: out = log_softmax([agg | h] @ [W2l;W2r] + b2) ----------------
__global__ __launch_bounds__(256) void layer2_kernel(
    const float* __restrict__ agg, const float* __restrict__ h,
    const float* __restrict__ W2l, const float* __restrict__ W2r,
    const float* __restrict__ b2, float* __restrict__ out) {
    __shared__ float a_tile[128][65];
    __shared__ float w_tile[64][40];
    const int t = threadIdx.x;
    const int node0 = blockIdx.x * 128;
    const int tr = t >> 3;
    const int tc = t & 7;

    float acc[4][5];
    #pragma unroll
    for (int m = 0; m < 4; ++m)
        #pragma unroll
        for (int r = 0; r < 5; ++r) acc[m][r] = 0.0f;

    for (int kc = 0; kc < 256; kc += 64) {
        #pragma unroll
        for (int i = 0; i < 8; ++i) {
            int idx = t + i * 256;
            int row = idx >> 4;
            int c4  = idx & 15;
            int n = node0 + row;
            int nc = (n < N_NODES) ? n : (N_NODES - 1);
            float4 v;
            if (kc < 128) {
                v = *reinterpret_cast<const float4*>(agg + (size_t)nc * 128 + kc + c4 * 4);
            } else {
                v = *reinterpret_cast<const float4*>(h + (size_t)nc * 128 + (kc - 128) + c4 * 4);
            }
            a_tile[row][c4 * 4 + 0] = v.x;
            a_tile[row][c4 * 4 + 1] = v.y;
            a_tile[row][c4 * 4 + 2] = v.z;
            a_tile[row][c4 * 4 + 3] = v.w;
        }
        #pragma unroll
        for (int i = 0; i < 10; ++i) {
            int idx = t + i * 256;
            int row = idx / 40;
            int col = idx % 40;
            int k = kc + row;
            float v = (k < 128) ? W2l[(size_t)k * 40 + col]
                                : W2r[(size_t)(k - 128) * 40 + col];
            w_tile[row][col] = v;
        }
        __syncthreads();
        #pragma unroll
        for (int kk = 0; kk < 64; ++kk) {
            float a0 = a_tile[tr * 4 + 0][kk];
            float a1 = a_tile[tr * 4 + 1][kk];
            float a2 = a_tile[tr * 4 + 2][kk];
            float a3 = a_tile[tr * 4 + 3][kk];
            float w[5];
            #pragma unroll
            for (int r = 0; r < 5; ++r) w[r] = w_tile[kk][tc * 5 + r];
            #pragma unroll
            for (int r = 0; r < 5; ++r) {
                acc[0][r] += a0 * w[r];
                acc[1][r] += a1 * w[r];
                acc[2][r] += a2 * w[r];
                acc[3][r] += a3 * w[r];
            }
        }
        __syncthreads();
    }
    #pragma unroll
    for (int m = 0; m < 4; ++m) {
        int n = node0 + tr * 4 + m;
        float v[5];
        float mx = -1e30f;
        #pragma unroll
        for (int r = 0; r < 5; ++r) {
            v[r] = acc[m][r] + b2[tc * 5 + r];
            mx = fmaxf(mx, v[r]);
        }
        #pragma unroll
        for (int s = 1; s < 8; s <<= 1) mx = fmaxf(mx, __shfl_xor(mx, s, 64));
        float se = 0.0f;
        #pragma unroll
        for (int r = 0; r < 5; ++r) se += expf(v[r] - mx);
        #pragma unroll
        for (int s = 1; s < 8; s <<= 1) se += __shfl_xor(se, s, 64);
        float lz = mx + logf(se);
        if (n < N_NODES) {
            #pragma unroll
            for (int r = 0; r < 5; ++r)
                out[(size_t)n * 40 + tc * 5 + r] = v[r] - lz;
        }
    }
}

// ---------------- launch ----------------
extern "C" void kernel_launch(void* const* d_in, const int* in_sizes, int n_in,
                              void* d_out, int out_size, void* d_ws, size_t ws_size,
                              hipStream_t stream) {
    const float* x   = (const float*)d_in[0];
    const void*  ei  = d_in[1];
    const float* W1l = (const float*)d_in[2];
    const float* b1  = (const float*)d_in[3];
    const float* W1r = (const float*)d_in[4];
    const float* W2l = (const float*)d_in[5];
    const float* b2  = (const float*)d_in[6];
    const float* W2r = (const float*)d_in[7];
    float* out = (float*)d_out;

    // ws: flag | agg | h   (<= 102.4 MB, inside validated footprint)
    char* ws = (char*)d_ws;
    int*   flag = (int*)ws;
    float* agg  = (float*)(ws + 4096);                 // 51.2 MB
    float* h    = (float*)(ws + 4096 + 51200000);      // 51.2 MB

    // d_out (16 MB) doubles as CSR scratch; all consumed before layer2
    // overwrites it with the real output.
    char* ob = (char*)d_out;
    int* csr    = (int*)ob;                            // 6.4 MB
    int* deg    = (int*)(ob + 6400000);                // 400 KB
    int* bsum   = (int*)(ob + 6800000);                // 1.6 KB
    int* cursor = (int*)(ob + 6801664);                // 400 KB (end: 7.2 MB)

    zero_i32<<<128, 256, 0, stream>>>(deg, N_NODES);
    zero_i32<<<1, 64, 0, stream>>>(flag, 1);
    detect_int64<<<1024, 256, 0, stream>>>((const int*)ei, flag);
    deg_count<<<2048, 256, 0, stream>>>(ei, flag, deg);
    scan1<<<NB_SCAN, 256, 0, stream>>>(deg, bsum);
    scan2<<<1, 512, 0, stream>>>(bsum);
    scan3<<<NB_SCAN, 256, 0, stream>>>(deg, bsum, cursor);
    csr_fill<<<2048, 256, 0, stream>>>(ei, flag, cursor, csr);

    aggregate_mean<<<(N_NODES + 3) / 4, 256, 0, stream>>>(x, csr, cursor, agg);
    layer1_kernel<<<(N_NODES + 63) / 64, 256, 0, stream>>>(agg, x, W1l, W1r, b1, h);
    aggregate_mean<<<(N_NODES + 3) / 4, 256, 0, stream>>>(h, csr, cursor, agg);
    layer2_kernel<<<(N_NODES + 127) / 128, 256, 0, stream>>>(agg, h, W2l, W2r, b2, out);
}

// Round 5
// 505.956 us; speedup vs baseline: 6.0378x; 1.4741x over previous
//
#include <hip/hip_runtime.h>
#include <stdint.h>
#include <stddef.h>

#define N_NODES 100000
#define N_EDGES 1600000
#define IN_CH 128
#define HID_CH 128
#define OUT_CH 40
#define NB_SCAN 391   // ceil(N_NODES/256)

typedef __attribute__((ext_vector_type(8))) short bf16x8;
typedef __attribute__((ext_vector_type(4))) float f32x4;

// ---------------- bf16 helpers ----------------
__device__ __forceinline__ ushort f2bf(float f) {
    uint32_t u = __float_as_uint(f);
    uint32_t r = (u + 0x7FFFu + ((u >> 16) & 1u)) >> 16;   // RNE
    return (ushort)r;
}
__device__ __forceinline__ float bf2f(ushort u) {
    return __uint_as_float(((uint32_t)u) << 16);
}

// ---------------- threefry2x32 (JAX PRNG, key = (0,42)) ----------------
__device__ __forceinline__ uint32_t rotl32(uint32_t x, int r) {
    return (x << r) | (x >> (32 - r));
}

__device__ __forceinline__ void threefry2x32_k42(uint32_t x0, uint32_t x1,
                                                 uint32_t& o0, uint32_t& o1) {
    const uint32_t ks0 = 0u, ks1 = 42u;
    const uint32_t ks2 = 0u ^ 42u ^ 0x1BD11BDAu;
    x0 += ks0; x1 += ks1;
    x0 += x1; x1 = rotl32(x1, 13); x1 ^= x0;
    x0 += x1; x1 = rotl32(x1, 15); x1 ^= x0;
    x0 += x1; x1 = rotl32(x1, 26); x1 ^= x0;
    x0 += x1; x1 = rotl32(x1,  6); x1 ^= x0;
    x0 += ks1; x1 += ks2 + 1u;
    x0 += x1; x1 = rotl32(x1, 17); x1 ^= x0;
    x0 += x1; x1 = rotl32(x1, 29); x1 ^= x0;
    x0 += x1; x1 = rotl32(x1, 16); x1 ^= x0;
    x0 += x1; x1 = rotl32(x1, 24); x1 ^= x0;
    x0 += ks2; x1 += ks0 + 2u;
    x0 += x1; x1 = rotl32(x1, 13); x1 ^= x0;
    x0 += x1; x1 = rotl32(x1, 15); x1 ^= x0;
    x0 += x1; x1 = rotl32(x1, 26); x1 ^= x0;
    x0 += x1; x1 = rotl32(x1,  6); x1 ^= x0;
    x0 += ks0; x1 += ks1 + 3u;
    x0 += x1; x1 = rotl32(x1, 17); x1 ^= x0;
    x0 += x1; x1 = rotl32(x1, 29); x1 ^= x0;
    x0 += x1; x1 = rotl32(x1, 16); x1 ^= x0;
    x0 += x1; x1 = rotl32(x1, 24); x1 ^= x0;
    x0 += ks1; x1 += ks2 + 4u;
    x0 += x1; x1 = rotl32(x1, 13); x1 ^= x0;
    x0 += x1; x1 = rotl32(x1, 15); x1 ^= x0;
    x0 += x1; x1 = rotl32(x1, 26); x1 ^= x0;
    x0 += x1; x1 = rotl32(x1,  6); x1 ^= x0;
    x0 += ks2; x1 += ks0 + 5u;
    o0 = x0; o1 = x1;
}

// Partitionable threefry bits[i] = o0 ^ o1 of block(counts=(0,i)); keep iff MSB==0.
// (Validated round 3: absmax 0.031.)
__device__ __forceinline__ float dropout_apply(float v, uint32_t idx) {
    uint32_t o0, o1;
    threefry2x32_k42(0u, idx, o0, o1);
    return ((o0 ^ o1) & 0x80000000u) ? 0.0f : v * 2.0f;
}

// ---------------- edge dtype detection ----------------
__global__ void detect_int64(const int* __restrict__ ei32, int* __restrict__ flag) {
    int i = blockIdx.x * blockDim.x + threadIdx.x;
    int stride = gridDim.x * blockDim.x;
    int local = 0;
    for (int k = i; k < N_EDGES; k += stride) local |= ei32[2 * k + 1];
    if (local) atomicOr(flag, 1);
}

__device__ __forceinline__ void load_edge(const void* ei, bool is32, int e,
                                          int& s, int& d) {
    if (is32) {
        const int* p = (const int*)ei;
        s = p[e]; d = p[N_EDGES + e];
    } else {
        const long long* p = (const long long*)ei;
        s = (int)p[e]; d = (int)p[N_EDGES + e];
    }
}

// ---------------- CSR build ----------------
__global__ void zero_i32(int* __restrict__ p, int n) {
    int i = blockIdx.x * blockDim.x + threadIdx.x;
    int stride = gridDim.x * blockDim.x;
    for (; i < n; i += stride) p[i] = 0;
}

__global__ void deg_count(const void* __restrict__ ei, const int* __restrict__ flag,
                          int* __restrict__ deg) {
    bool is32 = (*flag != 0);
    int i = blockIdx.x * blockDim.x + threadIdx.x;
    int stride = gridDim.x * blockDim.x;
    for (; i < N_EDGES; i += stride) {
        int s, d;
        load_edge(ei, is32, i, s, d);
        atomicAdd(&deg[d], 1);
    }
}

__global__ void scan1(const int* __restrict__ deg, int* __restrict__ bsum) {
    __shared__ int s[256];
    int t = threadIdx.x;
    int i = blockIdx.x * 256 + t;
    s[t] = (i < N_NODES) ? deg[i] : 0;
    __syncthreads();
    for (int off = 128; off; off >>= 1) {
        if (t < off) s[t] += s[t + off];
        __syncthreads();
    }
    if (t == 0) bsum[blockIdx.x] = s[0];
}

__global__ void scan2(int* __restrict__ bsum) {
    __shared__ int s[512];
    int t = threadIdx.x;
    int v = (t < NB_SCAN) ? bsum[t] : 0;
    s[t] = v;
    __syncthreads();
    for (int off = 1; off < 512; off <<= 1) {
        int a = (t >= off) ? s[t - off] : 0;
        __syncthreads();
        s[t] += a;
        __syncthreads();
    }
    if (t < NB_SCAN) bsum[t] = s[t] - v;   // exclusive
}

__global__ void scan3(const int* __restrict__ deg, const int* __restrict__ bsum,
                      int* __restrict__ cursor) {
    __shared__ int s[256];
    int t = threadIdx.x;
    int i = blockIdx.x * 256 + t;
    int v = (i < N_NODES) ? deg[i] : 0;
    s[t] = v;
    __syncthreads();
    for (int off = 1; off < 256; off <<= 1) {
        int a = (t >= off) ? s[t - off] : 0;
        __syncthreads();
        s[t] += a;
        __syncthreads();
    }
    if (i < N_NODES) cursor[i] = bsum[blockIdx.x] + s[t] - v;
}

// after fill, cursor[n] == end of node n's bucket
__global__ void csr_fill(const void* __restrict__ ei, const int* __restrict__ flag,
                         int* __restrict__ cursor, int* __restrict__ csr) {
    bool is32 = (*flag != 0);
    int i = blockIdx.x * blockDim.x + threadIdx.x;
    int stride = gridDim.x * blockDim.x;
    for (; i < N_EDGES; i += stride) {
        int s, d;
        load_edge(ei, is32, i, s, d);
        int p = atomicAdd(&cursor[d], 1);
        csr[p] = s;
    }
}

// ---------------- conversions ----------------
__global__ void cvt_f32_bf16(const float* __restrict__ in, ushort* __restrict__ out,
                             long n4) {
    long i = (long)blockIdx.x * blockDim.x + threadIdx.x;
    long stride = (long)gridDim.x * blockDim.x;
    for (; i < n4; i += stride) {
        float4 v = *reinterpret_cast<const float4*>(in + i * 4);
        ushort4 r;
        r.x = f2bf(v.x); r.y = f2bf(v.y); r.z = f2bf(v.z); r.w = f2bf(v.w);
        *reinterpret_cast<ushort4*>(out + i * 4) = r;
    }
}

// Wt[n][k] = bf16( k<128 ? Wl[k][n] : Wr[k-128][n] ), with n >= ncols -> 0
__global__ void cvt_w(const float* __restrict__ Wl, const float* __restrict__ Wr,
                      ushort* __restrict__ Wt, int ncols) {
    int n = blockIdx.x;
    int k = threadIdx.x;
    float v = 0.0f;
    if (n < ncols)
        v = (k < 128) ? Wl[(size_t)k * ncols + n] : Wr[(size_t)(k - 128) * ncols + n];
    Wt[(size_t)n * 256 + k] = f2bf(v);
}

// ---------------- gather-based mean aggregation (bf16 features) ----------------
__global__ __launch_bounds__(256) void aggregate_mean_bf(
    const ushort* __restrict__ feat, const int* __restrict__ csr,
    const int* __restrict__ cursor, ushort* __restrict__ out) {
    int node = blockIdx.x * 4 + (threadIdx.x >> 6);
    if (node >= N_NODES) return;
    int lane = threadIdx.x & 63;
    int beg = (node > 0) ? cursor[node - 1] : 0;
    int end = cursor[node];
    float ax0 = 0, ay0 = 0, ax1 = 0, ay1 = 0;
    float ax2 = 0, ay2 = 0, ax3 = 0, ay3 = 0;
    int e = beg;
    for (; e + 4 <= end; e += 4) {
        int s0 = csr[e], s1 = csr[e + 1], s2 = csr[e + 2], s3 = csr[e + 3];
        ushort2 v0 = *reinterpret_cast<const ushort2*>(feat + (size_t)s0 * 128 + lane * 2);
        ushort2 v1 = *reinterpret_cast<const ushort2*>(feat + (size_t)s1 * 128 + lane * 2);
        ushort2 v2 = *reinterpret_cast<const ushort2*>(feat + (size_t)s2 * 128 + lane * 2);
        ushort2 v3 = *reinterpret_cast<const ushort2*>(feat + (size_t)s3 * 128 + lane * 2);
        ax0 += bf2f(v0.x); ay0 += bf2f(v0.y);
        ax1 += bf2f(v1.x); ay1 += bf2f(v1.y);
        ax2 += bf2f(v2.x); ay2 += bf2f(v2.y);
        ax3 += bf2f(v3.x); ay3 += bf2f(v3.y);
    }
    for (; e < end; ++e) {
        ushort2 v = *reinterpret_cast<const ushort2*>(feat + (size_t)csr[e] * 128 + lane * 2);
        ax0 += bf2f(v.x); ay0 += bf2f(v.y);
    }
    int deg = end - beg;
    float inv = (deg > 0) ? (1.0f / (float)deg) : 0.0f;
    ushort2 r;
    r.x = f2bf((ax0 + ax1 + ax2 + ax3) * inv);
    r.y = f2bf((ay0 + ay1 + ay2 + ay3) * inv);
    *reinterpret_cast<ushort2*>(out + (size_t)node * 128 + lane * 2) = r;
}

// ---------------- layer 1 MFMA: h = dropout(relu([agg|x] @ W1' + b1)) ----------------
// 128 nodes/block, 4 waves, each wave 32 rows x 128 cols. No LDS, no barriers.
// A frag: a[j] = A[lane&15][kg*8+j]; B frag from transposed W: b[j] = Wt[col][k0+j].
__global__ __launch_bounds__(256) void layer1_mfma(
    const ushort* __restrict__ agg, const ushort* __restrict__ xbf,
    const ushort* __restrict__ Wt, const float* __restrict__ b1,
    ushort* __restrict__ h) {
    const int tid = threadIdx.x;
    const int wave = tid >> 6, lane = tid & 63;
    const int l15 = lane & 15, kg = lane >> 4;
    const int row_base = blockIdx.x * 128 + wave * 32;
    int r0 = row_base + l15;
    int r1 = r0 + 16;
    int r0c = (r0 < N_NODES) ? r0 : (N_NODES - 1);
    int r1c = (r1 < N_NODES) ? r1 : (N_NODES - 1);

    f32x4 acc[2][8];
    #pragma unroll
    for (int m = 0; m < 2; ++m)
        #pragma unroll
        for (int nf = 0; nf < 8; ++nf) acc[m][nf] = (f32x4){0.f, 0.f, 0.f, 0.f};

    #pragma unroll
    for (int ks = 0; ks < 8; ++ks) {
        const int kglob = ks * 32 + kg * 8;
        const ushort* abase = (kglob < 128) ? agg : xbf;
        const int koff = (kglob < 128) ? kglob : (kglob - 128);
        bf16x8 a0 = *reinterpret_cast<const bf16x8*>(abase + (size_t)r0c * 128 + koff);
        bf16x8 a1 = *reinterpret_cast<const bf16x8*>(abase + (size_t)r1c * 128 + koff);
        #pragma unroll
        for (int nf = 0; nf < 8; ++nf) {
            bf16x8 b = *reinterpret_cast<const bf16x8*>(
                Wt + (size_t)(nf * 16 + l15) * 256 + ks * 32 + kg * 8);
            acc[0][nf] = __builtin_amdgcn_mfma_f32_16x16x32_bf16(a0, b, acc[0][nf], 0, 0, 0);
            acc[1][nf] = __builtin_amdgcn_mfma_f32_16x16x32_bf16(a1, b, acc[1][nf], 0, 0, 0);
        }
    }

    // epilogue: bias + relu + dropout -> bf16 h
    #pragma unroll
    for (int m = 0; m < 2; ++m) {
        #pragma unroll
        for (int r = 0; r < 4; ++r) {
            int row = row_base + m * 16 + kg * 4 + r;
            if (row < N_NODES) {
                #pragma unroll
                for (int nf = 0; nf < 8; ++nf) {
                    int col = nf * 16 + l15;
                    float v = acc[m][nf][r] + b1[col];
                    v = fmaxf(v, 0.0f);
                    v = dropout_apply(v, (uint32_t)row * 128u + (uint32_t)col);
                    h[(size_t)row * 128 + col] = f2bf(v);
                }
            }
        }
    }
}

// ---------------- layer 2 MFMA: out = log_softmax([agg|h] @ W2' + b2) ----------------
// N padded to 48 (3 frags); cols 40..47 are zero in Wt2 and masked in epilogue.
__global__ __launch_bounds__(256) void layer2_mfma(
    const ushort* __restrict__ agg, const ushort* __restrict__ hbf,
    const ushort* __restrict__ Wt2, const float* __restrict__ b2,
    float* __restrict__ out) {
    const int tid = threadIdx.x;
    const int wave = tid >> 6, lane = tid & 63;
    const int l15 = lane & 15, kg = lane >> 4;
    const int row_base = blockIdx.x * 128 + wave * 32;
    int r0 = row_base + l15;
    int r1 = r0 + 16;
    int r0c = (r0 < N_NODES) ? r0 : (N_NODES - 1);
    int r1c = (r1 < N_NODES) ? r1 : (N_NODES - 1);

    f32x4 acc[2][3];
    #pragma unroll
    for (int m = 0; m < 2; ++m)
        #pragma unroll
        for (int nf = 0; nf < 3; ++nf) acc[m][nf] = (f32x4){0.f, 0.f, 0.f, 0.f};

    #pragma unroll
    for (int ks = 0; ks < 8; ++ks) {
        const int kglob = ks * 32 + kg * 8;
        const ushort* abase = (kglob < 128) ? agg : hbf;
        const int koff = (kglob < 128) ? kglob : (kglob - 128);
        bf16x8 a0 = *reinterpret_cast<const bf16x8*>(abase + (size_t)r0c * 128 + koff);
        bf16x8 a1 = *reinterpret_cast<const bf16x8*>(abase + (size_t)r1c * 128 + koff);
        #pragma unroll
        for (int nf = 0; nf < 3; ++nf) {
            bf16x8 b = *reinterpret_cast<const bf16x8*>(
                Wt2 + (size_t)(nf * 16 + l15) * 256 + ks * 32 + kg * 8);
            acc[0][nf] = __builtin_amdgcn_mfma_f32_16x16x32_bf16(a0, b, acc[0][nf], 0, 0, 0);
            acc[1][nf] = __builtin_amdgcn_mfma_f32_16x16x32_bf16(a1, b, acc[1][nf], 0, 0, 0);
        }
    }

    // epilogue: bias + masked row log_softmax (row spread over 16-lane group x 3 frags)
    #pragma unroll
    for (int m = 0; m < 2; ++m) {
        #pragma unroll
        for (int r = 0; r < 4; ++r) {
            int row = row_base + m * 16 + kg * 4 + r;
            float v[3];
            #pragma unroll
            for (int nf = 0; nf < 3; ++nf) {
                int col = nf * 16 + l15;
                v[nf] = (col < OUT_CH) ? (acc[m][nf][r] + b2[col]) : -3.0e38f;
            }
            float mx = fmaxf(fmaxf(v[0], v[1]), v[2]);
            #pragma unroll
            for (int s = 1; s < 16; s <<= 1) mx = fmaxf(mx, __shfl_xor(mx, s, 64));
            float se = 0.0f;
            #pragma unroll
            for (int nf = 0; nf < 3; ++nf) {
                int col = nf * 16 + l15;
                if (col < OUT_CH) se += expf(v[nf] - mx);
            }
            #pragma unroll
            for (int s = 1; s < 16; s <<= 1) se += __shfl_xor(se, s, 64);
            float lz = mx + logf(se);
            if (row < N_NODES) {
                #pragma unroll
                for (int nf = 0; nf < 3; ++nf) {
                    int col = nf * 16 + l15;
                    if (col < OUT_CH)
                        out[(size_t)row * OUT_CH + col] = v[nf] - lz;
                }
            }
        }
    }
}

// ---------------- launch ----------------
extern "C" void kernel_launch(void* const* d_in, const int* in_sizes, int n_in,
                              void* d_out, int out_size, void* d_ws, size_t ws_size,
                              hipStream_t stream) {
    const float* x   = (const float*)d_in[0];
    const void*  ei  = d_in[1];
    const float* W1l = (const float*)d_in[2];
    const float* b1  = (const float*)d_in[3];
    const float* W1r = (const float*)d_in[4];
    const float* W2l = (const float*)d_in[5];
    const float* b2  = (const float*)d_in[6];
    const float* W2r = (const float*)d_in[7];
    float* out = (float*)d_out;

    // ws: flag | x_bf | h_bf | agg_bf | Wt1 | Wt2   (~76.9 MB, under validated 102 MB)
    char* ws = (char*)d_ws;
    int*    flag   = (int*)ws;
    ushort* x_bf   = (ushort*)(ws + 4096);                    // 25.6 MB
    ushort* h_bf   = (ushort*)(ws + 4096 + 25600000);         // 25.6 MB
    ushort* agg_bf = (ushort*)(ws + 4096 + 51200000);         // 25.6 MB
    ushort* Wt1    = (ushort*)(ws + 4096 + 76800000);         // 64 KB  [128][256]
    ushort* Wt2    = (ushort*)(ws + 4096 + 76865536);         // 24 KB  [48][256]

    // d_out (16 MB) doubles as CSR scratch; fully consumed before layer2 writes.
    char* ob = (char*)d_out;
    int* csr    = (int*)ob;                            // 6.4 MB
    int* deg    = (int*)(ob + 6400000);                // 400 KB
    int* bsum   = (int*)(ob + 6800000);                // 1.6 KB
    int* cursor = (int*)(ob + 6801664);                // 400 KB

    zero_i32<<<128, 256, 0, stream>>>(deg, N_NODES);
    zero_i32<<<1, 64, 0, stream>>>(flag, 1);
    detect_int64<<<1024, 256, 0, stream>>>((const int*)ei, flag);
    deg_count<<<2048, 256, 0, stream>>>(ei, flag, deg);
    scan1<<<NB_SCAN, 256, 0, stream>>>(deg, bsum);
    scan2<<<1, 512, 0, stream>>>(bsum);
    scan3<<<NB_SCAN, 256, 0, stream>>>(deg, bsum, cursor);
    csr_fill<<<2048, 256, 0, stream>>>(ei, flag, cursor, csr);

    cvt_f32_bf16<<<2048, 256, 0, stream>>>(x, x_bf, (long)N_NODES * 128 / 4);
    cvt_w<<<128, 256, 0, stream>>>(W1l, W1r, Wt1, 128);
    cvt_w<<<48, 256, 0, stream>>>(W2l, W2r, Wt2, 40);

    aggregate_mean_bf<<<(N_NODES + 3) / 4, 256, 0, stream>>>(x_bf, csr, cursor, agg_bf);
    layer1_mfma<<<(N_NODES + 127) / 128, 256, 0, stream>>>(agg_bf, x_bf, Wt1, b1, h_bf);
    aggregate_mean_bf<<<(N_NODES + 3) / 4, 256, 0, stream>>>(h_bf, csr, cursor, agg_bf);
    layer2_mfma<<<(N_NODES + 127) / 128, 256, 0, stream>>>(agg_bf, h_bf, Wt2, b2, out);
}

// Round 6
// 417.694 us; speedup vs baseline: 7.3136x; 1.2113x over previous
//
#include <hip/hip_runtime.h>
#include <stdint.h>
#include <stddef.h>

#define N_NODES 100000
#define N_EDGES 1600000
#define IN_CH 128
#define HID_CH 128
#define OUT_CH 40

#define NB 196            // buckets: b = dst >> 9 (512 nodes each; 196*512 >= 100000)
#define NG 8              // blockIdx%8 sub-groups (approx XCD-local append streams)
#define BCAP 1792         // per-(g,b) capacity; mean 1024, sigma 32 -> +24 sigma

typedef __attribute__((ext_vector_type(8))) short bf16x8;
typedef __attribute__((ext_vector_type(4))) float f32x4;

// ---------------- bf16 helpers ----------------
__device__ __forceinline__ ushort f2bf(float f) {
    uint32_t u = __float_as_uint(f);
    uint32_t r = (u + 0x7FFFu + ((u >> 16) & 1u)) >> 16;   // RNE
    return (ushort)r;
}
__device__ __forceinline__ float bf2f(ushort u) {
    return __uint_as_float(((uint32_t)u) << 16);
}

// ---------------- threefry2x32 (JAX PRNG, key = (0,42)) ----------------
__device__ __forceinline__ uint32_t rotl32(uint32_t x, int r) {
    return (x << r) | (x >> (32 - r));
}

__device__ __forceinline__ void threefry2x32_k42(uint32_t x0, uint32_t x1,
                                                 uint32_t& o0, uint32_t& o1) {
    const uint32_t ks0 = 0u, ks1 = 42u;
    const uint32_t ks2 = 0u ^ 42u ^ 0x1BD11BDAu;
    x0 += ks0; x1 += ks1;
    x0 += x1; x1 = rotl32(x1, 13); x1 ^= x0;
    x0 += x1; x1 = rotl32(x1, 15); x1 ^= x0;
    x0 += x1; x1 = rotl32(x1, 26); x1 ^= x0;
    x0 += x1; x1 = rotl32(x1,  6); x1 ^= x0;
    x0 += ks1; x1 += ks2 + 1u;
    x0 += x1; x1 = rotl32(x1, 17); x1 ^= x0;
    x0 += x1; x1 = rotl32(x1, 29); x1 ^= x0;
    x0 += x1; x1 = rotl32(x1, 16); x1 ^= x0;
    x0 += x1; x1 = rotl32(x1, 24); x1 ^= x0;
    x0 += ks2; x1 += ks0 + 2u;
    x0 += x1; x1 = rotl32(x1, 13); x1 ^= x0;
    x0 += x1; x1 = rotl32(x1, 15); x1 ^= x0;
    x0 += x1; x1 = rotl32(x1, 26); x1 ^= x0;
    x0 += x1; x1 = rotl32(x1,  6); x1 ^= x0;
    x0 += ks0; x1 += ks1 + 3u;
    x0 += x1; x1 = rotl32(x1, 17); x1 ^= x0;
    x0 += x1; x1 = rotl32(x1, 29); x1 ^= x0;
    x0 += x1; x1 = rotl32(x1, 16); x1 ^= x0;
    x0 += x1; x1 = rotl32(x1, 24); x1 ^= x0;
    x0 += ks1; x1 += ks2 + 4u;
    x0 += x1; x1 = rotl32(x1, 13); x1 ^= x0;
    x0 += x1; x1 = rotl32(x1, 15); x1 ^= x0;
    x0 += x1; x1 = rotl32(x1, 26); x1 ^= x0;
    x0 += x1; x1 = rotl32(x1,  6); x1 ^= x0;
    x0 += ks2; x1 += ks0 + 5u;
    o0 = x0; o1 = x1;
}

// Partitionable threefry bits[i] = o0 ^ o1 of block(counts=(0,i)); keep iff MSB==0.
// (Validated round 3: absmax 0.031.)
__device__ __forceinline__ float dropout_apply(float v, uint32_t idx) {
    uint32_t o0, o1;
    threefry2x32_k42(0u, idx, o0, o1);
    return ((o0 ^ o1) & 0x80000000u) ? 0.0f : v * 2.0f;
}

// ---------------- edge dtype detection ----------------
__global__ void detect_int64(const int* __restrict__ ei32, int* __restrict__ flag) {
    int i = blockIdx.x * blockDim.x + threadIdx.x;
    int stride = gridDim.x * blockDim.x;
    int local = 0;
    for (int k = i; k < N_EDGES; k += stride) local |= ei32[2 * k + 1];
    if (local) atomicOr(flag, 1);
}

__device__ __forceinline__ void load_edge(const void* ei, bool is32, int e,
                                          int& s, int& d) {
    if (is32) {
        const int* p = (const int*)ei;
        s = p[e]; d = p[N_EDGES + e];
    } else {
        const long long* p = (const long long*)ei;
        s = (int)p[e]; d = (int)p[N_EDGES + e];
    }
}

__global__ void zero_i32(int* __restrict__ p, int n) {
    int i = blockIdx.x * blockDim.x + threadIdx.x;
    int stride = gridDim.x * blockDim.x;
    for (; i < n; i += stride) p[i] = 0;
}

// ---------------- bucketed CSR build ----------------
// pass 1: append (src,dst) into bucket (g,b); appends to one sub-bucket are
// sequential -> 8 pairs/line, mostly same-XCD -> line written back once.
// gcnt padded: one counter per 64B line (index *16).
__global__ __launch_bounds__(256) void bucket_edges(
    const void* __restrict__ ei, const int* __restrict__ flag,
    int* __restrict__ gcnt, uint2* __restrict__ gbuf) {
    bool is32 = (*flag != 0);
    int g = blockIdx.x & (NG - 1);
    int i = blockIdx.x * blockDim.x + threadIdx.x;
    int stride = gridDim.x * blockDim.x;
    for (; i < N_EDGES; i += stride) {
        int s, d;
        load_edge(ei, is32, i, s, d);
        int b = d >> 9;
        int pos = atomicAdd(&gcnt[(g * NB + b) * 16], 1);
        gbuf[(size_t)(g * NB + b) * BCAP + pos] = make_uint2((uint32_t)s, (uint32_t)d);
    }
}

// exclusive scan of bucket totals (196 values, 1 block)
__global__ void bucket_scan(const int* __restrict__ gcnt, int* __restrict__ bbase) {
    __shared__ int s[256];
    int t = threadIdx.x;
    int tot = 0;
    if (t < NB)
        for (int g = 0; g < NG; ++g) tot += gcnt[(g * NB + t) * 16];
    s[t] = tot;
    __syncthreads();
    for (int off = 1; off < 256; off <<= 1) {
        int a = (t >= off) ? s[t - off] : 0;
        __syncthreads();
        s[t] += a;
        __syncthreads();
    }
    if (t < NB) bbase[t] = s[t] - tot;   // exclusive
}

// pass 2: one WG per bucket. LDS histogram (= exact global degrees for this
// dst range), LDS scan, cursor write, then place edges into the bucket's
// contiguous csr slice (single-CU -> write-coalesced).
__global__ __launch_bounds__(256) void build_csr(
    const int* __restrict__ gcnt, const uint2* __restrict__ gbuf,
    const int* __restrict__ bbase, int* __restrict__ csr, int* __restrict__ cursor) {
    __shared__ int hist[512];
    __shared__ int excl[512];
    __shared__ int cur[512];
    __shared__ int psum[256];
    const int b = blockIdx.x;
    const int t = threadIdx.x;
    hist[t] = 0; hist[t + 256] = 0;
    __syncthreads();
    const int base = bbase[b];
    for (int g = 0; g < NG; ++g) {
        int cnt = gcnt[(g * NB + b) * 16];
        const uint2* src = gbuf + (size_t)(g * NB + b) * BCAP;
        for (int i = t; i < cnt; i += 256)
            atomicAdd(&hist[src[i].y & 511], 1);
    }
    __syncthreads();
    // exclusive scan of 512 via 256 pair-sums
    int h0 = hist[2 * t], h1 = hist[2 * t + 1];
    psum[t] = h0 + h1;
    __syncthreads();
    int v = psum[t];
    for (int off = 1; off < 256; off <<= 1) {
        int a = (t >= off) ? psum[t - off] : 0;
        __syncthreads();
        psum[t] += a;
        __syncthreads();
    }
    int pex = psum[t] - v;
    excl[2 * t] = pex;
    excl[2 * t + 1] = pex + h0;
    cur[2 * t] = pex;
    cur[2 * t + 1] = pex + h0;
    __syncthreads();
    // cursor[n] = end pointer of node n's bucket
    for (int j = t; j < 512; j += 256) {
        int node = b * 512 + j;
        if (node < N_NODES) cursor[node] = base + excl[j] + hist[j];
    }
    // place
    for (int g = 0; g < NG; ++g) {
        int cnt = gcnt[(g * NB + b) * 16];
        const uint2* src = gbuf + (size_t)(g * NB + b) * BCAP;
        for (int i = t; i < cnt; i += 256) {
            uint2 p = src[i];
            int pos = atomicAdd(&cur[p.y & 511], 1);
            csr[base + pos] = (int)p.x;
        }
    }
}

// ---------------- conversions ----------------
__global__ void cvt_f32_bf16(const float* __restrict__ in, ushort* __restrict__ out,
                             long n4) {
    long i = (long)blockIdx.x * blockDim.x + threadIdx.x;
    long stride = (long)gridDim.x * blockDim.x;
    for (; i < n4; i += stride) {
        float4 v = *reinterpret_cast<const float4*>(in + i * 4);
        ushort4 r;
        r.x = f2bf(v.x); r.y = f2bf(v.y); r.z = f2bf(v.z); r.w = f2bf(v.w);
        *reinterpret_cast<ushort4*>(out + i * 4) = r;
    }
}

// Wt[n][k] = bf16( k<128 ? Wl[k][n] : Wr[k-128][n] ), n >= ncols -> 0
__global__ void cvt_w(const float* __restrict__ Wl, const float* __restrict__ Wr,
                      ushort* __restrict__ Wt, int ncols) {
    int n = blockIdx.x;
    int k = threadIdx.x;
    float v = 0.0f;
    if (n < ncols)
        v = (k < 128) ? Wl[(size_t)k * ncols + n] : Wr[(size_t)(k - 128) * ncols + n];
    Wt[(size_t)n * 256 + k] = f2bf(v);
}

// ---------------- gather-based mean aggregation (bf16) ----------------
__global__ __launch_bounds__(256) void aggregate_mean_bf(
    const ushort* __restrict__ feat, const int* __restrict__ csr,
    const int* __restrict__ cursor, ushort* __restrict__ out) {
    int node = blockIdx.x * 4 + (threadIdx.x >> 6);
    if (node >= N_NODES) return;
    int lane = threadIdx.x & 63;
    int beg = (node > 0) ? cursor[node - 1] : 0;
    int end = cursor[node];
    float ax0 = 0, ay0 = 0, ax1 = 0, ay1 = 0;
    float ax2 = 0, ay2 = 0, ax3 = 0, ay3 = 0;
    int e = beg;
    for (; e + 4 <= end; e += 4) {
        int s0 = csr[e], s1 = csr[e + 1], s2 = csr[e + 2], s3 = csr[e + 3];
        ushort2 v0 = *reinterpret_cast<const ushort2*>(feat + (size_t)s0 * 128 + lane * 2);
        ushort2 v1 = *reinterpret_cast<const ushort2*>(feat + (size_t)s1 * 128 + lane * 2);
        ushort2 v2 = *reinterpret_cast<const ushort2*>(feat + (size_t)s2 * 128 + lane * 2);
        ushort2 v3 = *reinterpret_cast<const ushort2*>(feat + (size_t)s3 * 128 + lane * 2);
        ax0 += bf2f(v0.x); ay0 += bf2f(v0.y);
        ax1 += bf2f(v1.x); ay1 += bf2f(v1.y);
        ax2 += bf2f(v2.x); ay2 += bf2f(v2.y);
        ax3 += bf2f(v3.x); ay3 += bf2f(v3.y);
    }
    for (; e < end; ++e) {
        ushort2 v = *reinterpret_cast<const ushort2*>(feat + (size_t)csr[e] * 128 + lane * 2);
        ax0 += bf2f(v.x); ay0 += bf2f(v.y);
    }
    int deg = end - beg;
    float inv = (deg > 0) ? (1.0f / (float)deg) : 0.0f;
    ushort2 r;
    r.x = f2bf((ax0 + ax1 + ax2 + ax3) * inv);
    r.y = f2bf((ay0 + ay1 + ay2 + ay3) * inv);
    *reinterpret_cast<ushort2*>(out + (size_t)node * 128 + lane * 2) = r;
}

// ---------------- layer 1 MFMA: h = dropout(relu([agg|x] @ W1' + b1)) ----------------
__global__ __launch_bounds__(256) void layer1_mfma(
    const ushort* __restrict__ agg, const ushort* __restrict__ xbf,
    const ushort* __restrict__ Wt, const float* __restrict__ b1,
    ushort* __restrict__ h) {
    const int tid = threadIdx.x;
    const int wave = tid >> 6, lane = tid & 63;
    const int l15 = lane & 15, kg = lane >> 4;
    const int row_base = blockIdx.x * 128 + wave * 32;
    int r0 = row_base + l15;
    int r1 = r0 + 16;
    int r0c = (r0 < N_NODES) ? r0 : (N_NODES - 1);
    int r1c = (r1 < N_NODES) ? r1 : (N_NODES - 1);

    f32x4 acc[2][8];
    #pragma unroll
    for (int m = 0; m < 2; ++m)
        #pragma unroll
        for (int nf = 0; nf < 8; ++nf) acc[m][nf] = (f32x4){0.f, 0.f, 0.f, 0.f};

    #pragma unroll
    for (int ks = 0; ks < 8; ++ks) {
        const int kglob = ks * 32 + kg * 8;
        const ushort* abase = (kglob < 128) ? agg : xbf;
        const int koff = (kglob < 128) ? kglob : (kglob - 128);
        bf16x8 a0 = *reinterpret_cast<const bf16x8*>(abase + (size_t)r0c * 128 + koff);
        bf16x8 a1 = *reinterpret_cast<const bf16x8*>(abase + (size_t)r1c * 128 + koff);
        #pragma unroll
        for (int nf = 0; nf < 8; ++nf) {
            bf16x8 b = *reinterpret_cast<const bf16x8*>(
                Wt + (size_t)(nf * 16 + l15) * 256 + ks * 32 + kg * 8);
            acc[0][nf] = __builtin_amdgcn_mfma_f32_16x16x32_bf16(a0, b, acc[0][nf], 0, 0, 0);
            acc[1][nf] = __builtin_amdgcn_mfma_f32_16x16x32_bf16(a1, b, acc[1][nf], 0, 0, 0);
        }
    }

    #pragma unroll
    for (int m = 0; m < 2; ++m) {
        #pragma unroll
        for (int r = 0; r < 4; ++r) {
            int row = row_base + m * 16 + kg * 4 + r;
            if (row < N_NODES) {
                #pragma unroll
                for (int nf = 0; nf < 8; ++nf) {
                    int col = nf * 16 + l15;
                    float v = acc[m][nf][r] + b1[col];
                    v = fmaxf(v, 0.0f);
                    v = dropout_apply(v, (uint32_t)row * 128u + (uint32_t)col);
                    h[(size_t)row * 128 + col] = f2bf(v);
                }
            }
        }
    }
}

// ---------------- layer 2 MFMA: out = log_softmax([agg|h] @ W2' + b2) ----------------
__global__ __launch_bounds__(256) void layer2_mfma(
    const ushort* __restrict__ agg, const ushort* __restrict__ hbf,
    const ushort* __restrict__ Wt2, const float* __restrict__ b2,
    float* __restrict__ out) {
    const int tid = threadIdx.x;
    const int wave = tid >> 6, lane = tid & 63;
    const int l15 = lane & 15, kg = lane >> 4;
    const int row_base = blockIdx.x * 128 + wave * 32;
    int r0 = row_base + l15;
    int r1 = r0 + 16;
    int r0c = (r0 < N_NODES) ? r0 : (N_NODES - 1);
    int r1c = (r1 < N_NODES) ? r1 : (N_NODES - 1);

    f32x4 acc[2][3];
    #pragma unroll
    for (int m = 0; m < 2; ++m)
        #pragma unroll
        for (int nf = 0; nf < 3; ++nf) acc[m][nf] = (f32x4){0.f, 0.f, 0.f, 0.f};

    #pragma unroll
    for (int ks = 0; ks < 8; ++ks) {
        const int kglob = ks * 32 + kg * 8;
        const ushort* abase = (kglob < 128) ? agg : hbf;
        const int koff = (kglob < 128) ? kglob : (kglob - 128);
        bf16x8 a0 = *reinterpret_cast<const bf16x8*>(abase + (size_t)r0c * 128 + koff);
        bf16x8 a1 = *reinterpret_cast<const bf16x8*>(abase + (size_t)r1c * 128 + koff);
        #pragma unroll
        for (int nf = 0; nf < 3; ++nf) {
            bf16x8 b = *reinterpret_cast<const bf16x8*>(
                Wt2 + (size_t)(nf * 16 + l15) * 256 + ks * 32 + kg * 8);
            acc[0][nf] = __builtin_amdgcn_mfma_f32_16x16x32_bf16(a0, b, acc[0][nf], 0, 0, 0);
            acc[1][nf] = __builtin_amdgcn_mfma_f32_16x16x32_bf16(a1, b, acc[1][nf], 0, 0, 0);
        }
    }

    #pragma unroll
    for (int m = 0; m < 2; ++m) {
        #pragma unroll
        for (int r = 0; r < 4; ++r) {
            int row = row_base + m * 16 + kg * 4 + r;
            float v[3];
            #pragma unroll
            for (int nf = 0; nf < 3; ++nf) {
                int col = nf * 16 + l15;
                v[nf] = (col < OUT_CH) ? (acc[m][nf][r] + b2[col]) : -3.0e38f;
            }
            float mx = fmaxf(fmaxf(v[0], v[1]), v[2]);
            #pragma unroll
            for (int s = 1; s < 16; s <<= 1) mx = fmaxf(mx, __shfl_xor(mx, s, 64));
            float se = 0.0f;
            #pragma unroll
            for (int nf = 0; nf < 3; ++nf) {
                int col = nf * 16 + l15;
                if (col < OUT_CH) se += expf(v[nf] - mx);
            }
            #pragma unroll
            for (int s = 1; s < 16; s <<= 1) se += __shfl_xor(se, s, 64);
            float lz = mx + logf(se);
            if (row < N_NODES) {
                #pragma unroll
                for (int nf = 0; nf < 3; ++nf) {
                    int col = nf * 16 + l15;
                    if (col < OUT_CH)
                        out[(size_t)row * OUT_CH + col] = v[nf] - lz;
                }
            }
        }
    }
}

// ---------------- launch ----------------
extern "C" void kernel_launch(void* const* d_in, const int* in_sizes, int n_in,
                              void* d_out, int out_size, void* d_ws, size_t ws_size,
                              hipStream_t stream) {
    const float* x   = (const float*)d_in[0];
    const void*  ei  = d_in[1];
    const float* W1l = (const float*)d_in[2];
    const float* b1  = (const float*)d_in[3];
    const float* W1r = (const float*)d_in[4];
    const float* W2l = (const float*)d_in[5];
    const float* b2  = (const float*)d_in[6];
    const float* W2r = (const float*)d_in[7];
    float* out = (float*)d_out;

    // ws layout (~99.5 MB, under the 102.9 MB validated in rounds 3/4)
    char* ws = (char*)d_ws;
    int*    flag   = (int*)ws;
    int*    gcnt   = (int*)(ws + 4096);            // 1568 counters, 64B-strided (100,352 B)
    int*    bbase  = (int*)(ws + 106496);          // 196 ints
    ushort* x_bf   = (ushort*)(ws + 131072);       // 25.6 MB
    ushort* h_bf   = (ushort*)(ws + 131072 + 25600000);
    ushort* agg_bf = (ushort*)(ws + 131072 + 51200000);
    ushort* Wt1    = (ushort*)(ws + 131072 + 76800000);          // 64 KB
    ushort* Wt2    = (ushort*)(ws + 131072 + 76865536);          // 24 KB
    uint2*  gbuf   = (uint2*)(ws + 131072 + 76890112);           // 22.48 MB

    // d_out (16 MB) doubles as CSR scratch; fully consumed before layer2 writes.
    char* ob = (char*)d_out;
    int* csr    = (int*)ob;                        // 6.4 MB
    int* cursor = (int*)(ob + 6400000);            // 400 KB

    zero_i32<<<32, 256, 0, stream>>>(gcnt, NG * NB * 16);
    zero_i32<<<1, 64, 0, stream>>>(flag, 1);
    detect_int64<<<1024, 256, 0, stream>>>((const int*)ei, flag);

    bucket_edges<<<2048, 256, 0, stream>>>(ei, flag, gcnt, gbuf);
    bucket_scan<<<1, 256, 0, stream>>>(gcnt, bbase);
    build_csr<<<NB, 256, 0, stream>>>(gcnt, gbuf, bbase, csr, cursor);

    cvt_f32_bf16<<<2048, 256, 0, stream>>>(x, x_bf, (long)N_NODES * 128 / 4);
    cvt_w<<<128, 256, 0, stream>>>(W1l, W1r, Wt1, 128);
    cvt_w<<<48, 256, 0, stream>>>(W2l, W2r, Wt2, 40);

    aggregate_mean_bf<<<(N_NODES + 3) / 4, 256, 0, stream>>>(x_bf, csr, cursor, agg_bf);
    layer1_mfma<<<(N_NODES + 127) / 128, 256, 0, stream>>>(agg_bf, x_bf, Wt1, b1, h_bf);
    aggregate_mean_bf<<<(N_NODES + 3) / 4, 256, 0, stream>>>(h_bf, csr, cursor, agg_bf);
    layer2_mfma<<<(N_NODES + 127) / 128, 256, 0, stream>>>(agg_bf, h_bf, Wt2, b2, out);
}